// Round 1
// baseline (7549.986 us; speedup 1.0000x reference)
//
#include <hip/hip_runtime.h>
#include <math.h>

// Problem constants
#define BT     4096      // B*T tokens per pass
#define M_TOT  8192      // 2 passes stacked
#define KDIM   768
#define VDIM   50257
#define REWARD_SCALE 0.5
#define DIV_WEIGHT   0.1
#define EPS_COS      1e-8f

// GEMM tile config
#define BM 128
#define BN 128
#define BK 16
#define LDPAD 4          // pad leading dim: 128+4=132 floats

// ---------------------------------------------------------------------------
// Kernel 1: fused logits + exp + per-token sum-exp accumulation.
// Virtual A = concat(p2, p3) [8192 x 768], B = W^T (W is [V x D] row-major).
// Each block computes a 128x128 logits tile in registers, exps it, and
// accumulates per-token partial sums into g_sumexp[8192] (f64 atomics).
// ---------------------------------------------------------------------------
__global__ __launch_bounds__(256)
void logits_expsum_kernel(const float* __restrict__ p2,
                          const float* __restrict__ p3,
                          const float* __restrict__ W,
                          double* __restrict__ g_sumexp)
{
    __shared__ float As[BK][BM + LDPAD];
    __shared__ float Bs[BK][BN + LDPAD];
    __shared__ float rowsum[BM];

    const int tid     = threadIdx.x;
    const int rowBase = blockIdx.y * BM;   // token base
    const int colBase = blockIdx.x * BN;   // vocab base

    if (tid < BM) rowsum[tid] = 0.0f;

    float acc[8][8];
#pragma unroll
    for (int i = 0; i < 8; ++i)
#pragma unroll
        for (int j = 0; j < 8; ++j) acc[i][j] = 0.0f;

    const int ty = tid >> 4;     // 0..15
    const int tx = tid & 15;     // 0..15
    const int r0 = ty * 8;
    const int c0 = tx * 8;

    for (int k0 = 0; k0 < KDIM; k0 += BK) {
        __syncthreads();   // protect LDS from previous iteration's readers
        // --- stage A tile (128 rows x 16 k), transposed into As[k][m] ---
#pragma unroll
        for (int l = 0; l < 2; ++l) {
            int id  = tid + l * 256;       // 0..511
            int row = id >> 2;             // 0..127
            int kq  = id & 3;              // float4 index within k-slice
            int m   = rowBase + row;
            const float* src = (m < BT) ? (p2 + (size_t)m * KDIM)
                                        : (p3 + (size_t)(m - BT) * KDIM);
            float4 v = *(const float4*)(src + k0 + kq * 4);
            As[kq * 4 + 0][row] = v.x;
            As[kq * 4 + 1][row] = v.y;
            As[kq * 4 + 2][row] = v.z;
            As[kq * 4 + 3][row] = v.w;
        }
        // --- stage B tile (128 vocab rows x 16 k), transposed ---
#pragma unroll
        for (int l = 0; l < 2; ++l) {
            int id  = tid + l * 256;
            int row = id >> 2;
            int kq  = id & 3;
            int c   = colBase + row;
            int cs  = (c < VDIM) ? c : (VDIM - 1);   // clamp; masked in epilogue
            float4 v = *(const float4*)(W + (size_t)cs * KDIM + k0 + kq * 4);
            Bs[kq * 4 + 0][row] = v.x;
            Bs[kq * 4 + 1][row] = v.y;
            Bs[kq * 4 + 2][row] = v.z;
            Bs[kq * 4 + 3][row] = v.w;
        }
        __syncthreads();
        // --- compute ---
#pragma unroll
        for (int kk = 0; kk < BK; ++kk) {
            float a[8], b[8];
            *(float4*)&a[0] = *(const float4*)&As[kk][r0];
            *(float4*)&a[4] = *(const float4*)&As[kk][r0 + 4];
            *(float4*)&b[0] = *(const float4*)&Bs[kk][c0];
            *(float4*)&b[4] = *(const float4*)&Bs[kk][c0 + 4];
#pragma unroll
            for (int i = 0; i < 8; ++i)
#pragma unroll
                for (int j = 0; j < 8; ++j)
                    acc[i][j] = fmaf(a[i], b[j], acc[i][j]);
        }
    }

    // --- epilogue: exp + per-row reduction ---
    __syncthreads();
#pragma unroll
    for (int i = 0; i < 8; ++i) {
        float s = 0.0f;
#pragma unroll
        for (int j = 0; j < 8; ++j) {
            int c = colBase + c0 + j;
            if (c < VDIM) s += expf(acc[i][j]);   // logits in [-4,4]: no max needed
        }
        atomicAdd(&rowsum[r0 + i], s);
    }
    __syncthreads();
    if (tid < BM) {
        atomicAdd(&g_sumexp[rowBase + tid], (double)rowsum[tid]);
    }
}

// ---------------------------------------------------------------------------
// Kernel 2: per token-pair — target logits, cosine, scalar accumulation.
// scal[0]=sum_nll_p2, scal[1]=sum_nll_p3, scal[2]=sum_cos, scal[3]=valid_cnt
// ---------------------------------------------------------------------------
__global__ __launch_bounds__(256)
void finalize_tokens_kernel(const float* __restrict__ p2,
                            const float* __restrict__ p3,
                            const float* __restrict__ W,
                            const int*   __restrict__ targets,
                            const double* __restrict__ g_sumexp,
                            double* __restrict__ scal)
{
    const int t   = blockIdx.x;      // 0..4095
    const int tid = threadIdx.x;
    const int tg  = targets[t];
    const bool valid = (tg >= 0);
    const float* w = W + (size_t)(valid ? tg : 0) * KDIM;
    const float* a = p2 + (size_t)t * KDIM;
    const float* b = p3 + (size_t)t * KDIM;

    float s22 = 0.f, s33 = 0.f, s23 = 0.f, s2w = 0.f, s3w = 0.f;
    for (int i = tid; i < KDIM; i += 256) {
        float x = a[i], y = b[i], ww = w[i];
        s22 = fmaf(x, x, s22);
        s33 = fmaf(y, y, s33);
        s23 = fmaf(x, y, s23);
        s2w = fmaf(x, ww, s2w);
        s3w = fmaf(y, ww, s3w);
    }
    // wave (64-lane) reduce
#pragma unroll
    for (int off = 32; off > 0; off >>= 1) {
        s22 += __shfl_down(s22, off);
        s33 += __shfl_down(s33, off);
        s23 += __shfl_down(s23, off);
        s2w += __shfl_down(s2w, off);
        s3w += __shfl_down(s3w, off);
    }
    __shared__ float sm[5][4];
    const int wave = tid >> 6, lane = tid & 63;
    if (lane == 0) {
        sm[0][wave] = s22; sm[1][wave] = s33; sm[2][wave] = s23;
        sm[3][wave] = s2w; sm[4][wave] = s3w;
    }
    __syncthreads();
    if (tid == 0) {
        float S22 = sm[0][0] + sm[0][1] + sm[0][2] + sm[0][3];
        float S33 = sm[1][0] + sm[1][1] + sm[1][2] + sm[1][3];
        float S23 = sm[2][0] + sm[2][1] + sm[2][2] + sm[2][3];
        float S2w = sm[3][0] + sm[3][1] + sm[3][2] + sm[3][3];
        float S3w = sm[4][0] + sm[4][1] + sm[4][2] + sm[4][3];

        float n2 = fmaxf(sqrtf(S22), EPS_COS);
        float n3 = fmaxf(sqrtf(S33), EPS_COS);
        float cosv = S23 / (n2 * n3);
        atomicAdd(&scal[2], (double)cosv);

        if (valid) {
            double nll2 = log(g_sumexp[t])      - (double)S2w;
            double nll3 = log(g_sumexp[BT + t]) - (double)S3w;
            atomicAdd(&scal[0], nll2);
            atomicAdd(&scal[1], nll3);
            atomicAdd(&scal[3], 1.0);
        }
    }
}

// ---------------------------------------------------------------------------
// Kernel 3: combine into the output scalar.
// ---------------------------------------------------------------------------
__global__ void final_scalar_kernel(const double* __restrict__ scal,
                                    float* __restrict__ out)
{
    double cnt = (scal[3] > 0.0) ? scal[3] : 1.0;
    double loss_p2 = scal[0] / cnt;
    double loss_p3 = scal[1] / cnt;
    double reward_loss = -REWARD_SCALE * (loss_p2 - loss_p3);
    double divergence  =  DIV_WEIGHT * (scal[2] / (double)BT);
    out[0] = (float)(reward_loss + divergence);
}

// ---------------------------------------------------------------------------
extern "C" void kernel_launch(void* const* d_in, const int* in_sizes, int n_in,
                              void* d_out, int out_size, void* d_ws, size_t ws_size,
                              hipStream_t stream)
{
    const float* p2  = (const float*)d_in[0];   // [2,2048,768] fp32
    const float* p3  = (const float*)d_in[1];   // [2,2048,768] fp32
    const float* W   = (const float*)d_in[2];   // [50257,768] fp32
    const int*   tgt = (const int*)d_in[3];     // [2,2048] int

    double* g_sumexp = (double*)d_ws;           // 8192 doubles
    double* scal     = g_sumexp + M_TOT;        // 4 doubles

    hipMemsetAsync(d_ws, 0, (M_TOT + 4) * sizeof(double), stream);

    dim3 grid1((VDIM + BN - 1) / BN, M_TOT / BM);   // 393 x 64
    logits_expsum_kernel<<<grid1, dim3(256), 0, stream>>>(p2, p3, W, g_sumexp);

    finalize_tokens_kernel<<<dim3(BT), dim3(256), 0, stream>>>(
        p2, p3, W, tgt, g_sumexp, scal);

    final_scalar_kernel<<<dim3(1), dim3(1), 0, stream>>>(scal, (float*)d_out);
}

// Round 2
// 7436.858 us; speedup vs baseline: 1.0152x; 1.0152x over previous
//
#include <hip/hip_runtime.h>
#include <math.h>

// Problem constants
#define BT     4096      // B*T tokens per pass
#define M_TOT  8192      // 2 passes stacked
#define KDIM   768
#define VDIM   50257
#define REWARD_SCALE 0.5
#define DIV_WEIGHT   0.1
#define EPS_COS      1e-8f

// GEMM tile config
#define BM 128
#define BN 128
#define BK 16
#define LDPAD 4          // pad leading dim: 128+4=132 floats

// ---------------------------------------------------------------------------
// Kernel 1: fused logits + exp + per-token sum-exp accumulation.
// Virtual A = concat(p2, p3) [8192 x 768], B = W^T (W is [V x D] row-major).
// B-fragment is SPLIT (cols tx*4..+3 and 64+tx*4..+3) so each ds_read_b128
// has 16 lanes covering 256 contiguous bytes = all 32 banks 2-way (free),
// instead of the 4-way conflict of the contiguous-8 mapping.
// ---------------------------------------------------------------------------
__global__ __launch_bounds__(256)
void logits_expsum_kernel(const float* __restrict__ p2,
                          const float* __restrict__ p3,
                          const float* __restrict__ W,
                          double* __restrict__ g_sumexp)
{
    __shared__ float As[BK][BM + LDPAD];
    __shared__ float Bs[BK][BN + LDPAD];
    __shared__ float rowsum[BM];

    const int tid     = threadIdx.x;
    const int rowBase = blockIdx.y * BM;   // token base
    const int colBase = blockIdx.x * BN;   // vocab base

    if (tid < BM) rowsum[tid] = 0.0f;

    float acc[8][8];
#pragma unroll
    for (int i = 0; i < 8; ++i)
#pragma unroll
        for (int j = 0; j < 8; ++j) acc[i][j] = 0.0f;

    const int ty = tid >> 4;     // 0..15  (rows: broadcast within wave, free)
    const int tx = tid & 15;     // 0..15  (cols: split-4 mapping, 2-way free)
    const int r0 = ty * 8;
    const int c0 = tx * 4;       // first half: cols [c0, c0+4)
                                 // second half: cols [64+c0, 64+c0+4)

    for (int k0 = 0; k0 < KDIM; k0 += BK) {
        __syncthreads();   // protect LDS from previous iteration's readers
        // --- stage A tile (128 rows x 16 k), transposed into As[k][m] ---
#pragma unroll
        for (int l = 0; l < 2; ++l) {
            int id  = tid + l * 256;       // 0..511
            int row = id >> 2;             // 0..127
            int kq  = id & 3;              // float4 index within k-slice
            int m   = rowBase + row;
            const float* src = (m < BT) ? (p2 + (size_t)m * KDIM)
                                        : (p3 + (size_t)(m - BT) * KDIM);
            float4 v = *(const float4*)(src + k0 + kq * 4);
            As[kq * 4 + 0][row] = v.x;
            As[kq * 4 + 1][row] = v.y;
            As[kq * 4 + 2][row] = v.z;
            As[kq * 4 + 3][row] = v.w;
        }
        // --- stage B tile (128 vocab rows x 16 k), transposed ---
#pragma unroll
        for (int l = 0; l < 2; ++l) {
            int id  = tid + l * 256;
            int row = id >> 2;
            int kq  = id & 3;
            int c   = colBase + row;
            int cs  = (c < VDIM) ? c : (VDIM - 1);   // clamp; masked in epilogue
            float4 v = *(const float4*)(W + (size_t)cs * KDIM + k0 + kq * 4);
            Bs[kq * 4 + 0][row] = v.x;
            Bs[kq * 4 + 1][row] = v.y;
            Bs[kq * 4 + 2][row] = v.z;
            Bs[kq * 4 + 3][row] = v.w;
        }
        __syncthreads();
        // --- compute ---
#pragma unroll
        for (int kk = 0; kk < BK; ++kk) {
            float a[8], b[8];
            *(float4*)&a[0] = *(const float4*)&As[kk][r0];
            *(float4*)&a[4] = *(const float4*)&As[kk][r0 + 4];
            *(float4*)&b[0] = *(const float4*)&Bs[kk][c0];        // cols c0..c0+3
            *(float4*)&b[4] = *(const float4*)&Bs[kk][64 + c0];   // cols 64+c0..
#pragma unroll
            for (int i = 0; i < 8; ++i)
#pragma unroll
                for (int j = 0; j < 8; ++j)
                    acc[i][j] = fmaf(a[i], b[j], acc[i][j]);
        }
    }

    // --- epilogue: exp + per-row reduction ---
    __syncthreads();
#pragma unroll
    for (int i = 0; i < 8; ++i) {
        float s = 0.0f;
#pragma unroll
        for (int j = 0; j < 8; ++j) {
            int c = colBase + ((j < 4) ? (c0 + j) : (64 + c0 + (j - 4)));
            if (c < VDIM) s += expf(acc[i][j]);   // logits in [-4,4]: no max needed
        }
        atomicAdd(&rowsum[r0 + i], s);
    }
    __syncthreads();
    if (tid < BM) {
        atomicAdd(&g_sumexp[rowBase + tid], (double)rowsum[tid]);
    }
}

// ---------------------------------------------------------------------------
// Kernel 2: per token-pair — target logits, cosine, scalar accumulation.
// scal[0]=sum_nll_p2, scal[1]=sum_nll_p3, scal[2]=sum_cos, scal[3]=valid_cnt
// ---------------------------------------------------------------------------
__global__ __launch_bounds__(256)
void finalize_tokens_kernel(const float* __restrict__ p2,
                            const float* __restrict__ p3,
                            const float* __restrict__ W,
                            const int*   __restrict__ targets,
                            const double* __restrict__ g_sumexp,
                            double* __restrict__ scal)
{
    const int t   = blockIdx.x;      // 0..4095
    const int tid = threadIdx.x;
    const int tg  = targets[t];
    const bool valid = (tg >= 0);
    const float* w = W + (size_t)(valid ? tg : 0) * KDIM;
    const float* a = p2 + (size_t)t * KDIM;
    const float* b = p3 + (size_t)t * KDIM;

    float s22 = 0.f, s33 = 0.f, s23 = 0.f, s2w = 0.f, s3w = 0.f;
    for (int i = tid; i < KDIM; i += 256) {
        float x = a[i], y = b[i], ww = w[i];
        s22 = fmaf(x, x, s22);
        s33 = fmaf(y, y, s33);
        s23 = fmaf(x, y, s23);
        s2w = fmaf(x, ww, s2w);
        s3w = fmaf(y, ww, s3w);
    }
    // wave (64-lane) reduce
#pragma unroll
    for (int off = 32; off > 0; off >>= 1) {
        s22 += __shfl_down(s22, off);
        s33 += __shfl_down(s33, off);
        s23 += __shfl_down(s23, off);
        s2w += __shfl_down(s2w, off);
        s3w += __shfl_down(s3w, off);
    }
    __shared__ float sm[5][4];
    const int wave = tid >> 6, lane = tid & 63;
    if (lane == 0) {
        sm[0][wave] = s22; sm[1][wave] = s33; sm[2][wave] = s23;
        sm[3][wave] = s2w; sm[4][wave] = s3w;
    }
    __syncthreads();
    if (tid == 0) {
        float S22 = sm[0][0] + sm[0][1] + sm[0][2] + sm[0][3];
        float S33 = sm[1][0] + sm[1][1] + sm[1][2] + sm[1][3];
        float S23 = sm[2][0] + sm[2][1] + sm[2][2] + sm[2][3];
        float S2w = sm[3][0] + sm[3][1] + sm[3][2] + sm[3][3];
        float S3w = sm[4][0] + sm[4][1] + sm[4][2] + sm[4][3];

        float n2 = fmaxf(sqrtf(S22), EPS_COS);
        float n3 = fmaxf(sqrtf(S33), EPS_COS);
        float cosv = S23 / (n2 * n3);
        atomicAdd(&scal[2], (double)cosv);

        if (valid) {
            double nll2 = log(g_sumexp[t])      - (double)S2w;
            double nll3 = log(g_sumexp[BT + t]) - (double)S3w;
            atomicAdd(&scal[0], nll2);
            atomicAdd(&scal[1], nll3);
            atomicAdd(&scal[3], 1.0);
        }
    }
}

// ---------------------------------------------------------------------------
// Kernel 3: combine into the output scalar.
// ---------------------------------------------------------------------------
__global__ void final_scalar_kernel(const double* __restrict__ scal,
                                    float* __restrict__ out)
{
    double cnt = (scal[3] > 0.0) ? scal[3] : 1.0;
    double loss_p2 = scal[0] / cnt;
    double loss_p3 = scal[1] / cnt;
    double reward_loss = -REWARD_SCALE * (loss_p2 - loss_p3);
    double divergence  =  DIV_WEIGHT * (scal[2] / (double)BT);
    out[0] = (float)(reward_loss + divergence);
}

// ---------------------------------------------------------------------------
extern "C" void kernel_launch(void* const* d_in, const int* in_sizes, int n_in,
                              void* d_out, int out_size, void* d_ws, size_t ws_size,
                              hipStream_t stream)
{
    const float* p2  = (const float*)d_in[0];   // [2,2048,768] fp32
    const float* p3  = (const float*)d_in[1];   // [2,2048,768] fp32
    const float* W   = (const float*)d_in[2];   // [50257,768] fp32
    const int*   tgt = (const int*)d_in[3];     // [2,2048] int

    double* g_sumexp = (double*)d_ws;           // 8192 doubles
    double* scal     = g_sumexp + M_TOT;        // 4 doubles

    hipMemsetAsync(d_ws, 0, (M_TOT + 4) * sizeof(double), stream);

    dim3 grid1((VDIM + BN - 1) / BN, M_TOT / BM);   // 393 x 64
    logits_expsum_kernel<<<grid1, dim3(256), 0, stream>>>(p2, p3, W, g_sumexp);

    finalize_tokens_kernel<<<dim3(BT), dim3(256), 0, stream>>>(
        p2, p3, W, tgt, g_sumexp, scal);

    final_scalar_kernel<<<dim3(1), dim3(1), 0, stream>>>(scal, (float*)d_out);
}

// Round 3
// 2314.145 us; speedup vs baseline: 3.2625x; 3.2137x over previous
//
#include <hip/hip_runtime.h>
#include <math.h>

// Problem constants
#define BT     4096      // B*T tokens per pass
#define M_TOT  8192      // 2 passes stacked
#define KDIM   768
#define VDIM   50257
#define NBLK   393       // ceil(VDIM/128)
#define VPAD   (NBLK*128)
#define KCH    24        // 768 / 32 K-chunks
#define REWARD_SCALE 0.5
#define DIV_WEIGHT   0.1
#define EPS_COS      1e-8f
#define LO_SCALE 2048.0f
#define LO_INV   (1.0f/2048.0f)

typedef _Float16 half8 __attribute__((ext_vector_type(8)));
typedef float    f32x4 __attribute__((ext_vector_type(4)));

#define A_FRAGS (64*KCH*8*64)      // 786432  fragments of 16B
#define W_FRAGS (NBLK*KCH*8*64)    // 4829184 fragments of 16B

// ---------------------------------------------------------------------------
// async global->LDS, 16B per lane (wave-uniform base + lane*16 semantics)
// ---------------------------------------------------------------------------
__device__ __forceinline__ void g2l16(const short* g, short* l) {
    __builtin_amdgcn_global_load_lds(
        (const __attribute__((address_space(1))) unsigned int*)(const void*)g,
        (__attribute__((address_space(3))) unsigned int*)(void*)l,
        16, 0, 0);
}

// ---------------------------------------------------------------------------
// Converters: fp32 -> (hi, lo*2048) f16, pre-swizzled into MFMA fragment order.
// Frag index layout A: ((mb*24+k0)*8 + m_tile)*64 + lane
//   lane supplies A[m = mb*128+m_tile*16+(lane&15)][k = k0*32+(lane>>4)*8 + j]
// Frag index layout W: ((nb*24+k0)*8 + n_tile)*64 + lane  (B[n][k], n=lane&15)
// ---------------------------------------------------------------------------
__global__ __launch_bounds__(256)
void convert_A_kernel(const float* __restrict__ p2, const float* __restrict__ p3,
                      short* __restrict__ Ahi, short* __restrict__ Alo)
{
    int g = blockIdx.x * 256 + threadIdx.x;     // < 786432
    int lane = g & 63;
    int mt   = (g >> 6) & 7;
    int t    = g >> 9;            // mb*24 + k0
    int k0   = t % 24;
    int mb   = t / 24;
    int m = mb * 128 + mt * 16 + (lane & 15);
    int k = k0 * 32 + ((lane >> 4) << 3);
    const float* src = (m < BT) ? (p2 + (size_t)m * KDIM + k)
                                : (p3 + (size_t)(m - BT) * KDIM + k);
    float4 x0 = *(const float4*)src;
    float4 x1 = *(const float4*)(src + 4);
    float xs[8] = {x0.x, x0.y, x0.z, x0.w, x1.x, x1.y, x1.z, x1.w};
    half8 h, l;
#pragma unroll
    for (int j = 0; j < 8; ++j) {
        float x = xs[j];
        _Float16 hh = (_Float16)x;
        h[j] = hh;
        l[j] = (_Float16)((x - (float)hh) * LO_SCALE);
    }
    *(half8*)(Ahi + (size_t)g * 8) = h;
    *(half8*)(Alo + (size_t)g * 8) = l;
}

__global__ __launch_bounds__(256)
void convert_W_kernel(const float* __restrict__ W,
                      short* __restrict__ Whi, short* __restrict__ Wlo)
{
    int g = blockIdx.x * 256 + threadIdx.x;     // < 4829184
    int lane = g & 63;
    int nt   = (g >> 6) & 7;
    int t    = g >> 9;            // nb*24 + k0
    int k0   = t % 24;
    int nb   = t / 24;
    int v = nb * 128 + nt * 16 + (lane & 15);
    int k = k0 * 32 + ((lane >> 4) << 3);
    half8 h = (half8)(_Float16)0.0f, l = (half8)(_Float16)0.0f;
    if (v < VDIM) {
        const float* src = W + (size_t)v * KDIM + k;
        float4 x0 = *(const float4*)src;
        float4 x1 = *(const float4*)(src + 4);
        float xs[8] = {x0.x, x0.y, x0.z, x0.w, x1.x, x1.y, x1.z, x1.w};
#pragma unroll
        for (int j = 0; j < 8; ++j) {
            float x = xs[j];
            _Float16 hh = (_Float16)x;
            h[j] = hh;
            l[j] = (_Float16)((x - (float)hh) * LO_SCALE);
        }
    }
    *(half8*)(Whi + (size_t)g * 8) = h;
    *(half8*)(Wlo + (size_t)g * 8) = l;
}

// ---------------------------------------------------------------------------
// Main GEMM: 128x128 tile, BK=32, f16-split 3-MFMA per 16x16x32 tile.
// A-frags direct global->reg; B staged via double-buffered global_load_lds.
// Epilogue: logit = accH + accM*2^-11 -> exp -> per-row sums -> f64 atomics.
// ---------------------------------------------------------------------------
__global__ __launch_bounds__(256, 2)
void gemm_f16split_kernel(const short* __restrict__ Ahi, const short* __restrict__ Alo,
                          const short* __restrict__ Whi, const short* __restrict__ Wlo,
                          double* __restrict__ g_sumexp)
{
    __shared__ __align__(16) short Bs[2][16][64][8];  // [buf][chunk: hi 0-7, lo 8-15][lane][8]
    __shared__ float rowsum[128];

    const int tid    = threadIdx.x;
    const int lane   = tid & 63;
    const int wave   = tid >> 6;
    const int wave_m = wave >> 1;     // 0..1
    const int wave_n = wave & 1;      // 0..1
    const int mb = blockIdx.x;        // 0..63  (token blocks)
    const int nb = blockIdx.y;        // 0..392 (vocab blocks)

    if (tid < 128) rowsum[tid] = 0.0f;

    f32x4 accH[4][4], accM[4][4];
#pragma unroll
    for (int i = 0; i < 4; ++i)
#pragma unroll
        for (int j = 0; j < 4; ++j) {
            accH[i][j] = (f32x4)0.0f;
            accM[i][j] = (f32x4)0.0f;
        }

    const short* WhiB = Whi + (size_t)(nb * KCH) * 512 * 8;
    const short* WloB = Wlo + (size_t)(nb * KCH) * 512 * 8;
    short* BsFlat = &Bs[0][0][0][0];

    // stage k0=0 into buf 0
    {
        const short* hs = WhiB;
        const short* ls = WloB;
#pragma unroll
        for (int c = 0; c < 4; ++c) {
            int chunk = wave * 4 + c;
            const short* gsrc = (chunk < 8) ? (hs + (size_t)((chunk << 6) + lane) * 8)
                                            : (ls + (size_t)((((chunk - 8)) << 6) + lane) * 8);
            g2l16(gsrc, BsFlat + ((size_t)(chunk * 64 + lane)) * 8);
        }
    }

    for (int k0 = 0; k0 < KCH; ++k0) {
        const int cur = k0 & 1;
        // A-frags for this k0: direct global->reg (L2-hot, coalesced 1KB/instr)
        half8 aH[4], aL[4];
        {
            size_t abase = (size_t)((mb * KCH + k0) * 8) * 64 * 8;
#pragma unroll
            for (int tm = 0; tm < 4; ++tm) {
                size_t off = abase + ((size_t)((wave_m * 4 + tm) * 64 + lane)) * 8;
                aH[tm] = *(const half8*)(Ahi + off);
                aL[tm] = *(const half8*)(Alo + off);
            }
        }
        // barrier: drains my stage(k0) (issued one compute-phase ago) + A-frag loads
        __syncthreads();
        // prefetch B for k0+1 into the other buffer (hidden behind this k0's MFMAs)
        if (k0 + 1 < KCH) {
            const short* hs = WhiB + (size_t)(k0 + 1) * 512 * 8;
            const short* ls = WloB + (size_t)(k0 + 1) * 512 * 8;
            short* dstBase = BsFlat + (size_t)(cur ^ 1) * 16 * 64 * 8;
#pragma unroll
            for (int c = 0; c < 4; ++c) {
                int chunk = wave * 4 + c;
                const short* gsrc = (chunk < 8) ? (hs + (size_t)((chunk << 6) + lane) * 8)
                                                : (ls + (size_t)((((chunk - 8)) << 6) + lane) * 8);
                g2l16(gsrc, dstBase + ((size_t)(chunk * 64 + lane)) * 8);
            }
        }
        // B-frags from current buffer
        half8 bh[4], bl[4];
#pragma unroll
        for (int tn = 0; tn < 4; ++tn) {
            bh[tn] = *(const half8*)&Bs[cur][wave_n * 4 + tn][lane][0];
            bl[tn] = *(const half8*)&Bs[cur][8 + wave_n * 4 + tn][lane][0];
        }
        // 48 MFMAs, grouped so same-acc dependencies are 16 apart
#pragma unroll
        for (int tm = 0; tm < 4; ++tm)
#pragma unroll
            for (int tn = 0; tn < 4; ++tn)
                accH[tm][tn] = __builtin_amdgcn_mfma_f32_16x16x32_f16(aH[tm], bh[tn], accH[tm][tn], 0, 0, 0);
#pragma unroll
        for (int tm = 0; tm < 4; ++tm)
#pragma unroll
            for (int tn = 0; tn < 4; ++tn)
                accM[tm][tn] = __builtin_amdgcn_mfma_f32_16x16x32_f16(aL[tm], bh[tn], accM[tm][tn], 0, 0, 0);
#pragma unroll
        for (int tm = 0; tm < 4; ++tm)
#pragma unroll
            for (int tn = 0; tn < 4; ++tn)
                accM[tm][tn] = __builtin_amdgcn_mfma_f32_16x16x32_f16(aH[tm], bl[tn], accM[tm][tn], 0, 0, 0);
    }

    // --- epilogue: combine, exp, per-row reduce ---
    const int colBase = nb * 128 + wave_n * 64;
    const int quad = lane >> 4;
    const int cidx = lane & 15;
#pragma unroll
    for (int tm = 0; tm < 4; ++tm) {
#pragma unroll
        for (int r = 0; r < 4; ++r) {
            float s = 0.0f;
#pragma unroll
            for (int tn = 0; tn < 4; ++tn) {
                int col = colBase + tn * 16 + cidx;
                float logit = accH[tm][tn][r] + accM[tm][tn][r] * LO_INV;
                if (col < VDIM) s += expf(logit);
            }
            s += __shfl_xor(s, 1);
            s += __shfl_xor(s, 2);
            s += __shfl_xor(s, 4);
            s += __shfl_xor(s, 8);
            if (cidx == 0) {
                int row = wave_m * 64 + tm * 16 + quad * 4 + r;
                atomicAdd(&rowsum[row], s);
            }
        }
    }
    __syncthreads();
    if (tid < 128) {
        atomicAdd(&g_sumexp[(size_t)mb * 128 + tid], (double)rowsum[tid]);
    }
}

// ---------------------------------------------------------------------------
// Fallback fp32 GEMM (round-2 kernel) if workspace is too small.
// ---------------------------------------------------------------------------
#define BM 128
#define BN 128
#define BK 16
#define LDPAD 4
__global__ __launch_bounds__(256)
void logits_expsum_kernel(const float* __restrict__ p2,
                          const float* __restrict__ p3,
                          const float* __restrict__ W,
                          double* __restrict__ g_sumexp)
{
    __shared__ float As[BK][BM + LDPAD];
    __shared__ float Bsh[BK][BN + LDPAD];
    __shared__ float rowsum[BM];

    const int tid     = threadIdx.x;
    const int rowBase = blockIdx.y * BM;
    const int colBase = blockIdx.x * BN;

    if (tid < BM) rowsum[tid] = 0.0f;

    float acc[8][8];
#pragma unroll
    for (int i = 0; i < 8; ++i)
#pragma unroll
        for (int j = 0; j < 8; ++j) acc[i][j] = 0.0f;

    const int ty = tid >> 4;
    const int tx = tid & 15;
    const int r0 = ty * 8;
    const int c0 = tx * 4;

    for (int k0 = 0; k0 < KDIM; k0 += BK) {
        __syncthreads();
#pragma unroll
        for (int l = 0; l < 2; ++l) {
            int id  = tid + l * 256;
            int row = id >> 2;
            int kq  = id & 3;
            int m   = rowBase + row;
            const float* src = (m < BT) ? (p2 + (size_t)m * KDIM)
                                        : (p3 + (size_t)(m - BT) * KDIM);
            float4 v = *(const float4*)(src + k0 + kq * 4);
            As[kq * 4 + 0][row] = v.x;
            As[kq * 4 + 1][row] = v.y;
            As[kq * 4 + 2][row] = v.z;
            As[kq * 4 + 3][row] = v.w;
        }
#pragma unroll
        for (int l = 0; l < 2; ++l) {
            int id  = tid + l * 256;
            int row = id >> 2;
            int kq  = id & 3;
            int c   = colBase + row;
            int cs  = (c < VDIM) ? c : (VDIM - 1);
            float4 v = *(const float4*)(W + (size_t)cs * KDIM + k0 + kq * 4);
            Bsh[kq * 4 + 0][row] = v.x;
            Bsh[kq * 4 + 1][row] = v.y;
            Bsh[kq * 4 + 2][row] = v.z;
            Bsh[kq * 4 + 3][row] = v.w;
        }
        __syncthreads();
#pragma unroll
        for (int kk = 0; kk < BK; ++kk) {
            float a[8], b[8];
            *(float4*)&a[0] = *(const float4*)&As[kk][r0];
            *(float4*)&a[4] = *(const float4*)&As[kk][r0 + 4];
            *(float4*)&b[0] = *(const float4*)&Bsh[kk][c0];
            *(float4*)&b[4] = *(const float4*)&Bsh[kk][64 + c0];
#pragma unroll
            for (int i = 0; i < 8; ++i)
#pragma unroll
                for (int j = 0; j < 8; ++j)
                    acc[i][j] = fmaf(a[i], b[j], acc[i][j]);
        }
    }

    __syncthreads();
#pragma unroll
    for (int i = 0; i < 8; ++i) {
        float s = 0.0f;
#pragma unroll
        for (int j = 0; j < 8; ++j) {
            int c = colBase + ((j < 4) ? (c0 + j) : (64 + c0 + (j - 4)));
            if (c < VDIM) s += expf(acc[i][j]);
        }
        atomicAdd(&rowsum[r0 + i], s);
    }
    __syncthreads();
    if (tid < BM) {
        atomicAdd(&g_sumexp[rowBase + tid], (double)rowsum[tid]);
    }
}

// ---------------------------------------------------------------------------
// Kernel 2: per token-pair — exact fp32 target logits, cosine, scalar sums.
// scal[0]=sum_nll_p2, scal[1]=sum_nll_p3, scal[2]=sum_cos, scal[3]=valid_cnt
// ---------------------------------------------------------------------------
__global__ __launch_bounds__(256)
void finalize_tokens_kernel(const float* __restrict__ p2,
                            const float* __restrict__ p3,
                            const float* __restrict__ W,
                            const int*   __restrict__ targets,
                            const double* __restrict__ g_sumexp,
                            double* __restrict__ scal)
{
    const int t   = blockIdx.x;
    const int tid = threadIdx.x;
    const int tg  = targets[t];
    const bool valid = (tg >= 0);
    const float* w = W + (size_t)(valid ? tg : 0) * KDIM;
    const float* a = p2 + (size_t)t * KDIM;
    const float* b = p3 + (size_t)t * KDIM;

    float s22 = 0.f, s33 = 0.f, s23 = 0.f, s2w = 0.f, s3w = 0.f;
    for (int i = tid; i < KDIM; i += 256) {
        float x = a[i], y = b[i], ww = w[i];
        s22 = fmaf(x, x, s22);
        s33 = fmaf(y, y, s33);
        s23 = fmaf(x, y, s23);
        s2w = fmaf(x, ww, s2w);
        s3w = fmaf(y, ww, s3w);
    }
#pragma unroll
    for (int off = 32; off > 0; off >>= 1) {
        s22 += __shfl_down(s22, off);
        s33 += __shfl_down(s33, off);
        s23 += __shfl_down(s23, off);
        s2w += __shfl_down(s2w, off);
        s3w += __shfl_down(s3w, off);
    }
    __shared__ float sm[5][4];
    const int wave = tid >> 6, lane = tid & 63;
    if (lane == 0) {
        sm[0][wave] = s22; sm[1][wave] = s33; sm[2][wave] = s23;
        sm[3][wave] = s2w; sm[4][wave] = s3w;
    }
    __syncthreads();
    if (tid == 0) {
        float S22 = sm[0][0] + sm[0][1] + sm[0][2] + sm[0][3];
        float S33 = sm[1][0] + sm[1][1] + sm[1][2] + sm[1][3];
        float S23 = sm[2][0] + sm[2][1] + sm[2][2] + sm[2][3];
        float S2w = sm[3][0] + sm[3][1] + sm[3][2] + sm[3][3];
        float S3w = sm[4][0] + sm[4][1] + sm[4][2] + sm[4][3];

        float n2 = fmaxf(sqrtf(S22), EPS_COS);
        float n3 = fmaxf(sqrtf(S33), EPS_COS);
        float cosv = S23 / (n2 * n3);
        atomicAdd(&scal[2], (double)cosv);

        if (valid) {
            double nll2 = log(g_sumexp[t])      - (double)S2w;
            double nll3 = log(g_sumexp[BT + t]) - (double)S3w;
            atomicAdd(&scal[0], nll2);
            atomicAdd(&scal[1], nll3);
            atomicAdd(&scal[3], 1.0);
        }
    }
}

// ---------------------------------------------------------------------------
__global__ void final_scalar_kernel(const double* __restrict__ scal,
                                    float* __restrict__ out)
{
    double cnt = (scal[3] > 0.0) ? scal[3] : 1.0;
    double loss_p2 = scal[0] / cnt;
    double loss_p3 = scal[1] / cnt;
    double reward_loss = -REWARD_SCALE * (loss_p2 - loss_p3);
    double divergence  =  DIV_WEIGHT * (scal[2] / (double)BT);
    out[0] = (float)(reward_loss + divergence);
}

// ---------------------------------------------------------------------------
extern "C" void kernel_launch(void* const* d_in, const int* in_sizes, int n_in,
                              void* d_out, int out_size, void* d_ws, size_t ws_size,
                              hipStream_t stream)
{
    const float* p2  = (const float*)d_in[0];   // [2,2048,768] fp32
    const float* p3  = (const float*)d_in[1];   // [2,2048,768] fp32
    const float* W   = (const float*)d_in[2];   // [50257,768] fp32
    const int*   tgt = (const int*)d_in[3];     // [2,2048]

    double* g_sumexp = (double*)d_ws;           // 8192 doubles
    double* scal     = g_sumexp + M_TOT;        // 4 doubles

    hipMemsetAsync(d_ws, 0, 131072, stream);

    const size_t need = 131072 + (size_t)A_FRAGS * 16 * 2 + (size_t)W_FRAGS * 16 * 2;
    if (ws_size >= need) {
        short* Ahi = (short*)((char*)d_ws + 131072);
        short* Alo = Ahi + (size_t)A_FRAGS * 8;
        short* Whi = Alo + (size_t)A_FRAGS * 8;
        short* Wlo = Whi + (size_t)W_FRAGS * 8;

        convert_A_kernel<<<dim3(A_FRAGS / 256), dim3(256), 0, stream>>>(p2, p3, Ahi, Alo);
        convert_W_kernel<<<dim3(W_FRAGS / 256), dim3(256), 0, stream>>>(W, Whi, Wlo);
        gemm_f16split_kernel<<<dim3(64, NBLK), dim3(256), 0, stream>>>(Ahi, Alo, Whi, Wlo, g_sumexp);
    } else {
        logits_expsum_kernel<<<dim3(NBLK, 64), dim3(256), 0, stream>>>(p2, p3, W, g_sumexp);
    }

    finalize_tokens_kernel<<<dim3(BT), dim3(256), 0, stream>>>(
        p2, p3, W, tgt, g_sumexp, scal);

    final_scalar_kernel<<<dim3(1), dim3(1), 0, stream>>>(scal, (float*)d_out);
}

// Round 4
// 1159.552 us; speedup vs baseline: 6.5111x; 1.9957x over previous
//
#include <hip/hip_runtime.h>
#include <math.h>

// Problem constants
#define BT     4096      // B*T tokens per pass
#define M_TOT  8192      // 2 passes stacked
#define KDIM   768
#define VDIM   50257
#define NBLK   393       // ceil(VDIM/128)
#define KCH    24        // 768 / 32 K-chunks
#define REWARD_SCALE 0.5
#define DIV_WEIGHT   0.1
#define EPS_COS      1e-8f

typedef _Float16 half8 __attribute__((ext_vector_type(8)));
typedef float    f32x4 __attribute__((ext_vector_type(4)));

#define A_FRAGS (64*KCH*8*64)      // 786432  fragments of 16B (f16 hi only)
#define W_FRAGS (NBLK*KCH*8*64)    // 4829184 fragments of 16B

// ---------------------------------------------------------------------------
// Converters: fp32 -> f16 (round-to-nearest), pre-swizzled into MFMA fragment
// order.  Frag index layout A: ((mb*24+k0)*8 + m_tile)*64 + lane
//   lane supplies A[m = mb*128+m_tile*16+(lane&15)][k = k0*32+(lane>>4)*8 + j]
// W identical with n in place of m (B[n][k] operand layout).
// ---------------------------------------------------------------------------
__global__ __launch_bounds__(256)
void convert_A_kernel(const float* __restrict__ p2, const float* __restrict__ p3,
                      short* __restrict__ Ahi)
{
    int g = blockIdx.x * 256 + threadIdx.x;     // < 786432
    int lane = g & 63;
    int mt   = (g >> 6) & 7;
    int t    = g >> 9;            // mb*24 + k0
    int k0   = t % 24;
    int mb   = t / 24;
    int m = mb * 128 + mt * 16 + (lane & 15);
    int k = k0 * 32 + ((lane >> 4) << 3);
    const float* src = (m < BT) ? (p2 + (size_t)m * KDIM + k)
                                : (p3 + (size_t)(m - BT) * KDIM + k);
    float4 x0 = *(const float4*)src;
    float4 x1 = *(const float4*)(src + 4);
    float xs[8] = {x0.x, x0.y, x0.z, x0.w, x1.x, x1.y, x1.z, x1.w};
    half8 h;
#pragma unroll
    for (int j = 0; j < 8; ++j) h[j] = (_Float16)xs[j];
    *(half8*)(Ahi + (size_t)g * 8) = h;
}

__global__ __launch_bounds__(256)
void convert_W_kernel(const float* __restrict__ W, short* __restrict__ Whi)
{
    int g = blockIdx.x * 256 + threadIdx.x;     // < 4829184
    int lane = g & 63;
    int nt   = (g >> 6) & 7;
    int t    = g >> 9;            // nb*24 + k0
    int k0   = t % 24;
    int nb   = t / 24;
    int v = nb * 128 + nt * 16 + (lane & 15);
    int k = k0 * 32 + ((lane >> 4) << 3);
    half8 h = (half8)(_Float16)0.0f;
    if (v < VDIM) {
        const float* src = W + (size_t)v * KDIM + k;
        float4 x0 = *(const float4*)src;
        float4 x1 = *(const float4*)(src + 4);
        float xs[8] = {x0.x, x0.y, x0.z, x0.w, x1.x, x1.y, x1.z, x1.w};
#pragma unroll
        for (int j = 0; j < 8; ++j) h[j] = (_Float16)xs[j];
    }
    *(half8*)(Whi + (size_t)g * 8) = h;
}

// ---------------------------------------------------------------------------
// Main GEMM: 128x128 tile, BK=32, pure-f16 single MFMA per 16x16x32 tile.
// ALL operands direct global->register (L2/L3-hot, coalesced dwordx4).
// No LDS staging, no in-loop barriers -> compiler interleaves MFMA/loads
// with fine-grained vmcnt.  acc=64 VGPRs -> 3 blocks/CU.
// ---------------------------------------------------------------------------
__global__ __launch_bounds__(256, 3)
void gemm_f16_kernel(const short* __restrict__ Ahi, const short* __restrict__ Whi,
                     double* __restrict__ g_sumexp)
{
    __shared__ float rowsum[128];

    const int tid    = threadIdx.x;
    const int lane   = tid & 63;
    const int wave   = tid >> 6;
    const int wave_m = wave >> 1;     // 0..1
    const int wave_n = wave & 1;      // 0..1
    const int mb = blockIdx.x;        // 0..63  (token blocks)
    const int nb = blockIdx.y;        // 0..392 (vocab blocks)

    if (tid < 128) rowsum[tid] = 0.0f;

    f32x4 acc[4][4];
#pragma unroll
    for (int i = 0; i < 4; ++i)
#pragma unroll
        for (int j = 0; j < 4; ++j) acc[i][j] = (f32x4)0.0f;

    // per-k0 fragment blocks are 8*64 frags of 8 halves = 4096 halves
    const short* Abase = Ahi + (size_t)(mb * KCH) * 4096
                             + (size_t)((wave_m * 4) * 64 + lane) * 8;
    const short* Bbase = Whi + (size_t)(nb * KCH) * 4096
                             + (size_t)((wave_n * 4) * 64 + lane) * 8;

#pragma unroll 4
    for (int k0 = 0; k0 < KCH; ++k0) {
        half8 a[4], b[4];
        const short* ap = Abase + (size_t)k0 * 4096;
        const short* bp = Bbase + (size_t)k0 * 4096;
#pragma unroll
        for (int tm = 0; tm < 4; ++tm) a[tm] = *(const half8*)(ap + tm * 512);
#pragma unroll
        for (int tn = 0; tn < 4; ++tn) b[tn] = *(const half8*)(bp + tn * 512);
#pragma unroll
        for (int tm = 0; tm < 4; ++tm)
#pragma unroll
            for (int tn = 0; tn < 4; ++tn)
                acc[tm][tn] = __builtin_amdgcn_mfma_f32_16x16x32_f16(
                                  a[tm], b[tn], acc[tm][tn], 0, 0, 0);
    }

    // --- epilogue: exp, per-row reduce, f64 atomic per row ---
    __syncthreads();   // rowsum init visible
    const int colBase = nb * 128 + wave_n * 64;
    const int quad = lane >> 4;
    const int cidx = lane & 15;
#pragma unroll
    for (int tm = 0; tm < 4; ++tm) {
#pragma unroll
        for (int r = 0; r < 4; ++r) {
            float s = 0.0f;
#pragma unroll
            for (int tn = 0; tn < 4; ++tn) {
                int col = colBase + tn * 16 + cidx;
                if (col < VDIM) s += expf(acc[tm][tn][r]);  // logits in [-5,5]
            }
            s += __shfl_xor(s, 1);
            s += __shfl_xor(s, 2);
            s += __shfl_xor(s, 4);
            s += __shfl_xor(s, 8);
            if (cidx == 0) {
                int row = wave_m * 64 + tm * 16 + quad * 4 + r;
                atomicAdd(&rowsum[row], s);
            }
        }
    }
    __syncthreads();
    if (tid < 128) {
        atomicAdd(&g_sumexp[(size_t)mb * 128 + tid], (double)rowsum[tid]);
    }
}

// ---------------------------------------------------------------------------
// Fallback fp32 GEMM (round-2 kernel) if workspace is too small.
// ---------------------------------------------------------------------------
#define BM 128
#define BN 128
#define BK 16
#define LDPAD 4
__global__ __launch_bounds__(256)
void logits_expsum_kernel(const float* __restrict__ p2,
                          const float* __restrict__ p3,
                          const float* __restrict__ W,
                          double* __restrict__ g_sumexp)
{
    __shared__ float As[BK][BM + LDPAD];
    __shared__ float Bsh[BK][BN + LDPAD];
    __shared__ float rowsum[BM];

    const int tid     = threadIdx.x;
    const int rowBase = blockIdx.y * BM;
    const int colBase = blockIdx.x * BN;

    if (tid < BM) rowsum[tid] = 0.0f;

    float acc[8][8];
#pragma unroll
    for (int i = 0; i < 8; ++i)
#pragma unroll
        for (int j = 0; j < 8; ++j) acc[i][j] = 0.0f;

    const int ty = tid >> 4;
    const int tx = tid & 15;
    const int r0 = ty * 8;
    const int c0 = tx * 4;

    for (int k0 = 0; k0 < KDIM; k0 += BK) {
        __syncthreads();
#pragma unroll
        for (int l = 0; l < 2; ++l) {
            int id  = tid + l * 256;
            int row = id >> 2;
            int kq  = id & 3;
            int m   = rowBase + row;
            const float* src = (m < BT) ? (p2 + (size_t)m * KDIM)
                                        : (p3 + (size_t)(m - BT) * KDIM);
            float4 v = *(const float4*)(src + k0 + kq * 4);
            As[kq * 4 + 0][row] = v.x;
            As[kq * 4 + 1][row] = v.y;
            As[kq * 4 + 2][row] = v.z;
            As[kq * 4 + 3][row] = v.w;
        }
#pragma unroll
        for (int l = 0; l < 2; ++l) {
            int id  = tid + l * 256;
            int row = id >> 2;
            int kq  = id & 3;
            int c   = colBase + row;
            int cs  = (c < VDIM) ? c : (VDIM - 1);
            float4 v = *(const float4*)(W + (size_t)cs * KDIM + k0 + kq * 4);
            Bsh[kq * 4 + 0][row] = v.x;
            Bsh[kq * 4 + 1][row] = v.y;
            Bsh[kq * 4 + 2][row] = v.z;
            Bsh[kq * 4 + 3][row] = v.w;
        }
        __syncthreads();
#pragma unroll
        for (int kk = 0; kk < BK; ++kk) {
            float a[8], b[8];
            *(float4*)&a[0] = *(const float4*)&As[kk][r0];
            *(float4*)&a[4] = *(const float4*)&As[kk][r0 + 4];
            *(float4*)&b[0] = *(const float4*)&Bsh[kk][c0];
            *(float4*)&b[4] = *(const float4*)&Bsh[kk][64 + c0];
#pragma unroll
            for (int i = 0; i < 8; ++i)
#pragma unroll
                for (int j = 0; j < 8; ++j)
                    acc[i][j] = fmaf(a[i], b[j], acc[i][j]);
        }
    }

    __syncthreads();
#pragma unroll
    for (int i = 0; i < 8; ++i) {
        float s = 0.0f;
#pragma unroll
        for (int j = 0; j < 8; ++j) {
            int c = colBase + ((j < 4) ? (c0 + j) : (64 + c0 + (j - 4)));
            if (c < VDIM) s += expf(acc[i][j]);
        }
        atomicAdd(&rowsum[r0 + i], s);
    }
    __syncthreads();
    if (tid < BM) {
        atomicAdd(&g_sumexp[rowBase + tid], (double)rowsum[tid]);
    }
}

// ---------------------------------------------------------------------------
// Kernel 2: per token-pair — exact fp32 target logits, cosine, scalar sums.
// scal[0]=sum_nll_p2, scal[1]=sum_nll_p3, scal[2]=sum_cos, scal[3]=valid_cnt
// ---------------------------------------------------------------------------
__global__ __launch_bounds__(256)
void finalize_tokens_kernel(const float* __restrict__ p2,
                            const float* __restrict__ p3,
                            const float* __restrict__ W,
                            const int*   __restrict__ targets,
                            const double* __restrict__ g_sumexp,
                            double* __restrict__ scal)
{
    const int t   = blockIdx.x;
    const int tid = threadIdx.x;
    const int tg  = targets[t];
    const bool valid = (tg >= 0);
    const float* w = W + (size_t)(valid ? tg : 0) * KDIM;
    const float* a = p2 + (size_t)t * KDIM;
    const float* b = p3 + (size_t)t * KDIM;

    float s22 = 0.f, s33 = 0.f, s23 = 0.f, s2w = 0.f, s3w = 0.f;
    for (int i = tid; i < KDIM; i += 256) {
        float x = a[i], y = b[i], ww = w[i];
        s22 = fmaf(x, x, s22);
        s33 = fmaf(y, y, s33);
        s23 = fmaf(x, y, s23);
        s2w = fmaf(x, ww, s2w);
        s3w = fmaf(y, ww, s3w);
    }
#pragma unroll
    for (int off = 32; off > 0; off >>= 1) {
        s22 += __shfl_down(s22, off);
        s33 += __shfl_down(s33, off);
        s23 += __shfl_down(s23, off);
        s2w += __shfl_down(s2w, off);
        s3w += __shfl_down(s3w, off);
    }
    __shared__ float sm[5][4];
    const int wave = tid >> 6, lane = tid & 63;
    if (lane == 0) {
        sm[0][wave] = s22; sm[1][wave] = s33; sm[2][wave] = s23;
        sm[3][wave] = s2w; sm[4][wave] = s3w;
    }
    __syncthreads();
    if (tid == 0) {
        float S22 = sm[0][0] + sm[0][1] + sm[0][2] + sm[0][3];
        float S33 = sm[1][0] + sm[1][1] + sm[1][2] + sm[1][3];
        float S23 = sm[2][0] + sm[2][1] + sm[2][2] + sm[2][3];
        float S2w = sm[3][0] + sm[3][1] + sm[3][2] + sm[3][3];
        float S3w = sm[4][0] + sm[4][1] + sm[4][2] + sm[4][3];

        float n2 = fmaxf(sqrtf(S22), EPS_COS);
        float n3 = fmaxf(sqrtf(S33), EPS_COS);
        float cosv = S23 / (n2 * n3);
        atomicAdd(&scal[2], (double)cosv);

        if (valid) {
            double nll2 = log(g_sumexp[t])      - (double)S2w;
            double nll3 = log(g_sumexp[BT + t]) - (double)S3w;
            atomicAdd(&scal[0], nll2);
            atomicAdd(&scal[1], nll3);
            atomicAdd(&scal[3], 1.0);
        }
    }
}

// ---------------------------------------------------------------------------
__global__ void final_scalar_kernel(const double* __restrict__ scal,
                                    float* __restrict__ out)
{
    double cnt = (scal[3] > 0.0) ? scal[3] : 1.0;
    double loss_p2 = scal[0] / cnt;
    double loss_p3 = scal[1] / cnt;
    double reward_loss = -REWARD_SCALE * (loss_p2 - loss_p3);
    double divergence  =  DIV_WEIGHT * (scal[2] / (double)BT);
    out[0] = (float)(reward_loss + divergence);
}

// ---------------------------------------------------------------------------
extern "C" void kernel_launch(void* const* d_in, const int* in_sizes, int n_in,
                              void* d_out, int out_size, void* d_ws, size_t ws_size,
                              hipStream_t stream)
{
    const float* p2  = (const float*)d_in[0];   // [2,2048,768] fp32
    const float* p3  = (const float*)d_in[1];   // [2,2048,768] fp32
    const float* W   = (const float*)d_in[2];   // [50257,768] fp32
    const int*   tgt = (const int*)d_in[3];     // [2,2048]

    double* g_sumexp = (double*)d_ws;           // 8192 doubles
    double* scal     = g_sumexp + M_TOT;        // 4 doubles

    hipMemsetAsync(d_ws, 0, 131072, stream);

    const size_t need = 131072 + (size_t)A_FRAGS * 16 + (size_t)W_FRAGS * 16;
    if (ws_size >= need) {
        short* Ahi = (short*)((char*)d_ws + 131072);
        short* Whi = Ahi + (size_t)A_FRAGS * 8;

        convert_A_kernel<<<dim3(A_FRAGS / 256), dim3(256), 0, stream>>>(p2, p3, Ahi);
        convert_W_kernel<<<dim3(W_FRAGS / 256), dim3(256), 0, stream>>>(W, Whi);
        // grid: x=mb fast -> the 8 same-XCD blocks per nb share W slice in L2,
        // and each XCD keeps its 8 A-slices (1.6 MB) L2-resident across nb.
        gemm_f16_kernel<<<dim3(64, NBLK), dim3(256), 0, stream>>>(Ahi, Whi, g_sumexp);
    } else {
        logits_expsum_kernel<<<dim3(NBLK, 64), dim3(256), 0, stream>>>(p2, p3, W, g_sumexp);
    }

    finalize_tokens_kernel<<<dim3(BT), dim3(256), 0, stream>>>(
        p2, p3, W, tgt, g_sumexp, scal);

    final_scalar_kernel<<<dim3(1), dim3(1), 0, stream>>>(scal, (float*)d_out);
}

// Round 5
// 1147.194 us; speedup vs baseline: 6.5813x; 1.0108x over previous
//
#include <hip/hip_runtime.h>
#include <math.h>

// Problem constants
#define BT     4096      // B*T tokens per pass
#define M_TOT  8192      // 2 passes stacked
#define KDIM   768
#define VDIM   50257
#define NBLK   393       // ceil(VDIM/128)
#define KCH    24        // 768 / 32 K-chunks
#define REWARD_SCALE 0.5
#define DIV_WEIGHT   0.1
#define EPS_COS      1e-8f

typedef _Float16 half8 __attribute__((ext_vector_type(8)));
typedef float    f32x4 __attribute__((ext_vector_type(4)));

#define A_FRAGS (64*KCH*8*64)      // 786432  fragments of 16B (f16)
#define W_FRAGS (NBLK*KCH*8*64)    // 4829184 fragments of 16B

// ---------------------------------------------------------------------------
// async global->LDS, 16B per lane (wave-uniform base + lane*16 semantics)
// ---------------------------------------------------------------------------
__device__ __forceinline__ void g2l16(const short* g, short* l) {
    __builtin_amdgcn_global_load_lds(
        (const __attribute__((address_space(1))) unsigned int*)(const void*)g,
        (__attribute__((address_space(3))) unsigned int*)(void*)l,
        16, 0, 0);
}

// ---------------------------------------------------------------------------
// Converters: fp32 -> f16, pre-swizzled into MFMA fragment order, with
// coalesced global reads via an LDS transpose (old version did strided 32B
// gathers -> ~4x overfetch).
// One block = one (128-row, 32-k) chunk.  Output frag layout:
//   ((blk*KCH + k0)*8 + tile)*64 + lane ; lane gives
//   [row = blk*128 + tile*16 + (lane&15)][k = k0*32 + (lane>>4)*8 + j]
// ---------------------------------------------------------------------------
__global__ __launch_bounds__(256)
void convert_A_kernel(const float* __restrict__ p2, const float* __restrict__ p3,
                      short* __restrict__ Ahi)
{
    __shared__ float Ls[128][36];          // pad 36: 16B-aligned, conflict-free
    const int mb = blockIdx.x;             // 0..63
    const int k0 = blockIdx.y;             // 0..23
    const int tid = threadIdx.x;

    // coalesced load: 4 passes, each thread one float4
#pragma unroll
    for (int p = 0; p < 4; ++p) {
        int i = p * 1024 + tid * 4;        // linear idx in 128x32 chunk
        int r = i >> 5;
        int c = i & 31;
        int m = mb * 128 + r;
        const float* src = (m < BT) ? (p2 + (size_t)m * KDIM)
                                    : (p3 + (size_t)(m - BT) * KDIM);
        float4 v = *(const float4*)(src + k0 * 32 + c);
        *(float4*)&Ls[r][c] = v;
    }
    __syncthreads();

    // each thread emits 2 fragments (512 frag-slots / 256 threads)
    size_t base = ((size_t)(mb * KCH + k0) * 8) * 64;
#pragma unroll
    for (int h = 0; h < 2; ++h) {
        int f    = tid + h * 256;          // tile*64 + lane
        int lane = f & 63;
        int tile = f >> 6;
        int row  = tile * 16 + (lane & 15);
        int kq   = (lane >> 4) * 8;
        half8 out;
#pragma unroll
        for (int j = 0; j < 8; ++j) out[j] = (_Float16)Ls[row][kq + j];
        *(half8*)(Ahi + (base + f) * 8) = out;
    }
}

__global__ __launch_bounds__(256)
void convert_W_kernel(const float* __restrict__ W, short* __restrict__ Whi)
{
    __shared__ float Ls[128][36];
    const int nb = blockIdx.x;             // 0..392
    const int k0 = blockIdx.y;             // 0..23
    const int tid = threadIdx.x;

#pragma unroll
    for (int p = 0; p < 4; ++p) {
        int i = p * 1024 + tid * 4;
        int r = i >> 5;
        int c = i & 31;
        int v = nb * 128 + r;
        float4 val = make_float4(0.f, 0.f, 0.f, 0.f);
        if (v < VDIM) val = *(const float4*)(W + (size_t)v * KDIM + k0 * 32 + c);
        *(float4*)&Ls[r][c] = val;
    }
    __syncthreads();

    size_t base = ((size_t)(nb * KCH + k0) * 8) * 64;
#pragma unroll
    for (int h = 0; h < 2; ++h) {
        int f    = tid + h * 256;
        int lane = f & 63;
        int tile = f >> 6;
        int row  = tile * 16 + (lane & 15);
        int kq   = (lane >> 4) * 8;
        half8 out;
#pragma unroll
        for (int j = 0; j < 8; ++j) out[j] = (_Float16)Ls[row][kq + j];
        *(half8*)(Whi + (base + f) * 8) = out;
    }
}

// ---------------------------------------------------------------------------
// Main GEMM: 256x128 block tile, 512 threads (8 waves, 4x2), wave tile 64x64.
// Both operands staged global->LDS via global_load_lds (VMEM pipe carries each
// byte ONCE: 24 KB / 4.2e6 FLOP per block-iter => ~41 B/cyc/CU at 2 blk/CU,
// under the ~60 B/cyc VMEM pipe ceiling that pinned rounds 3-4 at 41% MFMA).
// Double-buffered, one barrier per k0; prefetch has a full compute phase.
// ---------------------------------------------------------------------------
__global__ __launch_bounds__(512, 4)
void gemm_f16_kernel(const short* __restrict__ Ahi, const short* __restrict__ Whi,
                     double* __restrict__ g_sumexp)
{
    // A: 16 tiles (256 rows), B: 8 tiles (128 cols); tile t covers rows t*16..
    __shared__ __align__(16) short As[2][16][64][8];   // 32 KB
    __shared__ __align__(16) short Bs[2][8][64][8];    // 16 KB
    __shared__ float rowsum[256];                      // 1 KB

    const int tid    = threadIdx.x;
    const int lane   = tid & 63;
    const int wave   = tid >> 6;      // 0..7
    const int wave_m = wave >> 1;     // 0..3
    const int wave_n = wave & 1;      // 0..1
    const int mb2 = blockIdx.x;       // 0..31  (256-token blocks)
    const int nb  = blockIdx.y;       // 0..392 (128-vocab blocks)

    if (tid < 256) rowsum[tid] = 0.0f;

    f32x4 acc[4][4];
#pragma unroll
    for (int i = 0; i < 4; ++i)
#pragma unroll
        for (int j = 0; j < 4; ++j) acc[i][j] = (f32x4)0.0f;

    // stage helper: 24 chunks (16 A + 8 B), 3 per wave, 16B per lane.
    // A chunk c (0..15): old 128-block = 2*mb2 + (c>>3), tile-in-old = c&7
    //   (covers rows c*16..c*16+15 of the 256-row tile — linear, verified).
    // B chunk c (16..23): tile ct = c-16.
    const size_t Aroot = (size_t)(2 * mb2) * KCH * 4096;   // halves
    const size_t Broot = (size_t)nb * KCH * 4096;

#define STAGE(k0_, buf_)                                                      \
    {                                                                         \
        _Pragma("unroll")                                                     \
        for (int j = 0; j < 3; ++j) {                                         \
            int c = wave * 3 + j;                                             \
            const short* gsrc;                                                \
            short* ldst;                                                      \
            if (c < 16) {                                                     \
                gsrc = Ahi + Aroot + (size_t)(c >> 3) * KCH * 4096            \
                           + (size_t)(k0_) * 4096 + ((c & 7) * 64 + lane) * 8;\
                ldst = &As[buf_][c][lane][0];                                 \
            } else {                                                          \
                gsrc = Whi + Broot + (size_t)(k0_) * 4096                     \
                           + ((c - 16) * 64 + lane) * 8;                      \
                ldst = &Bs[buf_][c - 16][lane][0];                            \
            }                                                                 \
            g2l16(gsrc, ldst);                                                \
        }                                                                     \
    }

    STAGE(0, 0);

#pragma unroll 2
    for (int k0 = 0; k0 < KCH; ++k0) {
        const int buf = k0 & 1;
        __syncthreads();                    // drains stage(k0) (vmcnt in barrier)
        if (k0 + 1 < KCH) STAGE(k0 + 1, buf ^ 1);
        half8 a[4], b[4];
#pragma unroll
        for (int tm = 0; tm < 4; ++tm)
            a[tm] = *(const half8*)&As[buf][wave_m * 4 + tm][lane][0];
#pragma unroll
        for (int tn = 0; tn < 4; ++tn)
            b[tn] = *(const half8*)&Bs[buf][wave_n * 4 + tn][lane][0];
#pragma unroll
        for (int tm = 0; tm < 4; ++tm)
#pragma unroll
            for (int tn = 0; tn < 4; ++tn)
                acc[tm][tn] = __builtin_amdgcn_mfma_f32_16x16x32_f16(
                                  a[tm], b[tn], acc[tm][tn], 0, 0, 0);
    }
#undef STAGE

    // --- epilogue: exp, per-row reduce, f64 atomic per row ---
    __syncthreads();
    const int colBase = nb * 128 + wave_n * 64;
    const int quad = lane >> 4;
    const int cidx = lane & 15;
#pragma unroll
    for (int tm = 0; tm < 4; ++tm) {
#pragma unroll
        for (int r = 0; r < 4; ++r) {
            float s = 0.0f;
#pragma unroll
            for (int tn = 0; tn < 4; ++tn) {
                int col = colBase + tn * 16 + cidx;
                if (col < VDIM) s += expf(acc[tm][tn][r]);
            }
            s += __shfl_xor(s, 1);
            s += __shfl_xor(s, 2);
            s += __shfl_xor(s, 4);
            s += __shfl_xor(s, 8);
            if (cidx == 0) {
                int row = wave_m * 64 + tm * 16 + quad * 4 + r;
                atomicAdd(&rowsum[row], s);
            }
        }
    }
    __syncthreads();
    if (tid < 256) {
        atomicAdd(&g_sumexp[(size_t)mb2 * 256 + tid], (double)rowsum[tid]);
    }
}

// ---------------------------------------------------------------------------
// Fallback fp32 GEMM (round-2 kernel) if workspace is too small.
// ---------------------------------------------------------------------------
#define BM 128
#define BN 128
#define BK 16
#define LDPAD 4
__global__ __launch_bounds__(256)
void logits_expsum_kernel(const float* __restrict__ p2,
                          const float* __restrict__ p3,
                          const float* __restrict__ W,
                          double* __restrict__ g_sumexp)
{
    __shared__ float As[BK][BM + LDPAD];
    __shared__ float Bsh[BK][BN + LDPAD];
    __shared__ float rowsum[BM];

    const int tid     = threadIdx.x;
    const int rowBase = blockIdx.y * BM;
    const int colBase = blockIdx.x * BN;

    if (tid < BM) rowsum[tid] = 0.0f;

    float acc[8][8];
#pragma unroll
    for (int i = 0; i < 8; ++i)
#pragma unroll
        for (int j = 0; j < 8; ++j) acc[i][j] = 0.0f;

    const int ty = tid >> 4;
    const int tx = tid & 15;
    const int r0 = ty * 8;
    const int c0 = tx * 4;

    for (int k0 = 0; k0 < KDIM; k0 += BK) {
        __syncthreads();
#pragma unroll
        for (int l = 0; l < 2; ++l) {
            int id  = tid + l * 256;
            int row = id >> 2;
            int kq  = id & 3;
            int m   = rowBase + row;
            const float* src = (m < BT) ? (p2 + (size_t)m * KDIM)
                                        : (p3 + (size_t)(m - BT) * KDIM);
            float4 v = *(const float4*)(src + k0 + kq * 4);
            As[kq * 4 + 0][row] = v.x;
            As[kq * 4 + 1][row] = v.y;
            As[kq * 4 + 2][row] = v.z;
            As[kq * 4 + 3][row] = v.w;
        }
#pragma unroll
        for (int l = 0; l < 2; ++l) {
            int id  = tid + l * 256;
            int row = id >> 2;
            int kq  = id & 3;
            int c   = colBase + row;
            int cs  = (c < VDIM) ? c : (VDIM - 1);
            float4 v = *(const float4*)(W + (size_t)cs * KDIM + k0 + kq * 4);
            Bsh[kq * 4 + 0][row] = v.x;
            Bsh[kq * 4 + 1][row] = v.y;
            Bsh[kq * 4 + 2][row] = v.z;
            Bsh[kq * 4 + 3][row] = v.w;
        }
        __syncthreads();
#pragma unroll
        for (int kk = 0; kk < BK; ++kk) {
            float a[8], b[8];
            *(float4*)&a[0] = *(const float4*)&As[kk][r0];
            *(float4*)&a[4] = *(const float4*)&As[kk][r0 + 4];
            *(float4*)&b[0] = *(const float4*)&Bsh[kk][c0];
            *(float4*)&b[4] = *(const float4*)&Bsh[kk][64 + c0];
#pragma unroll
            for (int i = 0; i < 8; ++i)
#pragma unroll
                for (int j = 0; j < 8; ++j)
                    acc[i][j] = fmaf(a[i], b[j], acc[i][j]);
        }
    }

    __syncthreads();
#pragma unroll
    for (int i = 0; i < 8; ++i) {
        float s = 0.0f;
#pragma unroll
        for (int j = 0; j < 8; ++j) {
            int c = colBase + ((j < 4) ? (c0 + j) : (64 + c0 + (j - 4)));
            if (c < VDIM) s += expf(acc[i][j]);
        }
        atomicAdd(&rowsum[r0 + i], s);
    }
    __syncthreads();
    if (tid < BM) {
        atomicAdd(&g_sumexp[rowBase + tid], (double)rowsum[tid]);
    }
}

// ---------------------------------------------------------------------------
// Kernel 2: per token-pair — exact fp32 target logits, cosine, scalar sums.
// scal[0]=sum_nll_p2, scal[1]=sum_nll_p3, scal[2]=sum_cos, scal[3]=valid_cnt
// ---------------------------------------------------------------------------
__global__ __launch_bounds__(256)
void finalize_tokens_kernel(const float* __restrict__ p2,
                            const float* __restrict__ p3,
                            const float* __restrict__ W,
                            const int*   __restrict__ targets,
                            const double* __restrict__ g_sumexp,
                            double* __restrict__ scal)
{
    const int t   = blockIdx.x;
    const int tid = threadIdx.x;
    const int tg  = targets[t];
    const bool valid = (tg >= 0);
    const float* w = W + (size_t)(valid ? tg : 0) * KDIM;
    const float* a = p2 + (size_t)t * KDIM;
    const float* b = p3 + (size_t)t * KDIM;

    float s22 = 0.f, s33 = 0.f, s23 = 0.f, s2w = 0.f, s3w = 0.f;
    for (int i = tid; i < KDIM; i += 256) {
        float x = a[i], y = b[i], ww = w[i];
        s22 = fmaf(x, x, s22);
        s33 = fmaf(y, y, s33);
        s23 = fmaf(x, y, s23);
        s2w = fmaf(x, ww, s2w);
        s3w = fmaf(y, ww, s3w);
    }
#pragma unroll
    for (int off = 32; off > 0; off >>= 1) {
        s22 += __shfl_down(s22, off);
        s33 += __shfl_down(s33, off);
        s23 += __shfl_down(s23, off);
        s2w += __shfl_down(s2w, off);
        s3w += __shfl_down(s3w, off);
    }
    __shared__ float sm[5][4];
    const int wave = tid >> 6, lane = tid & 63;
    if (lane == 0) {
        sm[0][wave] = s22; sm[1][wave] = s33; sm[2][wave] = s23;
        sm[3][wave] = s2w; sm[4][wave] = s3w;
    }
    __syncthreads();
    if (tid == 0) {
        float S22 = sm[0][0] + sm[0][1] + sm[0][2] + sm[0][3];
        float S33 = sm[1][0] + sm[1][1] + sm[1][2] + sm[1][3];
        float S23 = sm[2][0] + sm[2][1] + sm[2][2] + sm[2][3];
        float S2w = sm[3][0] + sm[3][1] + sm[3][2] + sm[3][3];
        float S3w = sm[4][0] + sm[4][1] + sm[4][2] + sm[4][3];

        float n2 = fmaxf(sqrtf(S22), EPS_COS);
        float n3 = fmaxf(sqrtf(S33), EPS_COS);
        float cosv = S23 / (n2 * n3);
        atomicAdd(&scal[2], (double)cosv);

        if (valid) {
            double nll2 = log(g_sumexp[t])      - (double)S2w;
            double nll3 = log(g_sumexp[BT + t]) - (double)S3w;
            atomicAdd(&scal[0], nll2);
            atomicAdd(&scal[1], nll3);
            atomicAdd(&scal[3], 1.0);
        }
    }
}

// ---------------------------------------------------------------------------
__global__ void final_scalar_kernel(const double* __restrict__ scal,
                                    float* __restrict__ out)
{
    double cnt = (scal[3] > 0.0) ? scal[3] : 1.0;
    double loss_p2 = scal[0] / cnt;
    double loss_p3 = scal[1] / cnt;
    double reward_loss = -REWARD_SCALE * (loss_p2 - loss_p3);
    double divergence  =  DIV_WEIGHT * (scal[2] / (double)BT);
    out[0] = (float)(reward_loss + divergence);
}

// ---------------------------------------------------------------------------
extern "C" void kernel_launch(void* const* d_in, const int* in_sizes, int n_in,
                              void* d_out, int out_size, void* d_ws, size_t ws_size,
                              hipStream_t stream)
{
    const float* p2  = (const float*)d_in[0];   // [2,2048,768] fp32
    const float* p3  = (const float*)d_in[1];   // [2,2048,768] fp32
    const float* W   = (const float*)d_in[2];   // [50257,768] fp32
    const int*   tgt = (const int*)d_in[3];     // [2,2048]

    double* g_sumexp = (double*)d_ws;           // 8192 doubles
    double* scal     = g_sumexp + M_TOT;        // 4 doubles

    hipMemsetAsync(d_ws, 0, 131072, stream);

    const size_t need = 131072 + (size_t)A_FRAGS * 16 + (size_t)W_FRAGS * 16;
    if (ws_size >= need) {
        short* Ahi = (short*)((char*)d_ws + 131072);
        short* Whi = Ahi + (size_t)A_FRAGS * 8;

        convert_A_kernel<<<dim3(64, KCH), dim3(256), 0, stream>>>(p2, p3, Ahi);
        convert_W_kernel<<<dim3(NBLK, KCH), dim3(256), 0, stream>>>(W, Whi);
        gemm_f16_kernel<<<dim3(32, NBLK), dim3(512), 0, stream>>>(Ahi, Whi, g_sumexp);
    } else {
        logits_expsum_kernel<<<dim3(NBLK, 64), dim3(256), 0, stream>>>(p2, p3, W, g_sumexp);
    }

    finalize_tokens_kernel<<<dim3(BT), dim3(256), 0, stream>>>(
        p2, p3, W, tgt, g_sumexp, scal);

    final_scalar_kernel<<<dim3(1), dim3(1), 0, stream>>>(scal, (float*)d_out);
}

// Round 6
// 908.123 us; speedup vs baseline: 8.3138x; 1.2633x over previous
//
#include <hip/hip_runtime.h>
#include <math.h>

// Problem constants
#define BT     4096      // B*T tokens per pass
#define M_TOT  8192      // 2 passes stacked
#define KDIM   768
#define VDIM   50257
#define NBLK   393       // ceil(VDIM/128)
#define KCH    24        // 768 / 32 K-chunks
#define REWARD_SCALE 0.5
#define DIV_WEIGHT   0.1
#define EPS_COS      1e-8f
#define LOG2E        1.44269504088896340736f

typedef _Float16 half8 __attribute__((ext_vector_type(8)));
typedef float    f32x4 __attribute__((ext_vector_type(4)));

#define A_FRAGS (64*KCH*8*64)      // 786432  fragments of 16B (f16)
#define W_FRAGS (NBLK*KCH*8*64)    // 4829184 fragments of 16B

// ---------------------------------------------------------------------------
// async global->LDS, 16B per lane (wave-uniform base + lane*16 semantics)
// ---------------------------------------------------------------------------
__device__ __forceinline__ void g2l16(const short* g, short* l) {
    __builtin_amdgcn_global_load_lds(
        (const __attribute__((address_space(1))) unsigned int*)(const void*)g,
        (__attribute__((address_space(3))) unsigned int*)(void*)l,
        16, 0, 0);
}

// ---------------------------------------------------------------------------
// Converters: fp32 -> f16, pre-swizzled into MFMA fragment order (LDS
// transpose for coalesced reads).  W additionally scaled by log2(e) so the
// GEMM's logits come out in base-2 (epilogue = single v_exp_f32).
// Frag layout: ((blk*KCH + k0)*8 + tile)*64 + lane ; lane gives
//   [row = blk*128 + tile*16 + (lane&15)][k = k0*32 + (lane>>4)*8 + j]
// ---------------------------------------------------------------------------
__global__ __launch_bounds__(256)
void convert_A_kernel(const float* __restrict__ p2, const float* __restrict__ p3,
                      short* __restrict__ Ahi)
{
    __shared__ float Ls[128][36];
    const int mb = blockIdx.x;             // 0..63
    const int k0 = blockIdx.y;             // 0..23
    const int tid = threadIdx.x;

#pragma unroll
    for (int p = 0; p < 4; ++p) {
        int i = p * 1024 + tid * 4;
        int r = i >> 5;
        int c = i & 31;
        int m = mb * 128 + r;
        const float* src = (m < BT) ? (p2 + (size_t)m * KDIM)
                                    : (p3 + (size_t)(m - BT) * KDIM);
        float4 v = *(const float4*)(src + k0 * 32 + c);
        *(float4*)&Ls[r][c] = v;
    }
    __syncthreads();

    size_t base = ((size_t)(mb * KCH + k0) * 8) * 64;
#pragma unroll
    for (int h = 0; h < 2; ++h) {
        int f    = tid + h * 256;
        int lane = f & 63;
        int tile = f >> 6;
        int row  = tile * 16 + (lane & 15);
        int kq   = (lane >> 4) * 8;
        half8 out;
#pragma unroll
        for (int j = 0; j < 8; ++j) out[j] = (_Float16)Ls[row][kq + j];
        *(half8*)(Ahi + (base + f) * 8) = out;
    }
}

__global__ __launch_bounds__(256)
void convert_W_kernel(const float* __restrict__ W, short* __restrict__ Whi)
{
    __shared__ float Ls[128][36];
    const int nb = blockIdx.x;             // 0..392
    const int k0 = blockIdx.y;             // 0..23
    const int tid = threadIdx.x;

#pragma unroll
    for (int p = 0; p < 4; ++p) {
        int i = p * 1024 + tid * 4;
        int r = i >> 5;
        int c = i & 31;
        int v = nb * 128 + r;
        float4 val = make_float4(0.f, 0.f, 0.f, 0.f);
        if (v < VDIM) val = *(const float4*)(W + (size_t)v * KDIM + k0 * 32 + c);
        *(float4*)&Ls[r][c] = val;
    }
    __syncthreads();

    size_t base = ((size_t)(nb * KCH + k0) * 8) * 64;
#pragma unroll
    for (int h = 0; h < 2; ++h) {
        int f    = tid + h * 256;
        int lane = f & 63;
        int tile = f >> 6;
        int row  = tile * 16 + (lane & 15);
        int kq   = (lane >> 4) * 8;
        half8 out;
#pragma unroll
        for (int j = 0; j < 8; ++j) out[j] = (_Float16)(Ls[row][kq + j] * LOG2E);
        *(half8*)(Whi + (base + f) * 8) = out;
    }
}

// ---------------------------------------------------------------------------
// Main GEMM: 128x128 block tile, 256 threads (4 waves 2x2), wave tile 64x64.
// Pipe-split operand feed (r4 was VMEM-pinned, r5 LDS-pinned; both at 41%):
//   A: global_load_lds double-buffered (4 ds_read_b128/wave/k0 ~ 62% LDS pipe)
//   B: direct global->VGPR, register double-buffered prefetch (L2-resident,
//      ~53 B/cyc VMEM with L1 assist).
// Logits come out pre-scaled by log2e -> epilogue exp is one v_exp_f32.
// ---------------------------------------------------------------------------
__global__ __launch_bounds__(256, 4)
void gemm_f16_kernel(const short* __restrict__ Ahi, const short* __restrict__ Whi,
                     double* __restrict__ g_sumexp)
{
    __shared__ __align__(16) short As[2][8][64][8];   // 16 KB
    __shared__ float rowsum[128];

    const int tid    = threadIdx.x;
    const int lane   = tid & 63;
    const int wave   = tid >> 6;      // 0..3
    const int wave_m = wave >> 1;     // 0..1
    const int wave_n = wave & 1;      // 0..1
    const int mb = blockIdx.x;        // 0..63  (token blocks)
    const int nb = blockIdx.y;        // 0..392 (vocab blocks)

    if (tid < 128) rowsum[tid] = 0.0f;

    f32x4 acc[4][4];
#pragma unroll
    for (int i = 0; i < 4; ++i)
#pragma unroll
        for (int j = 0; j < 4; ++j) acc[i][j] = (f32x4)0.0f;

    // A frag halves offset: mb*KCH*4096 + (k0*8 + chunk)*512 + lane*8
    const short* Ablk  = Ahi + (size_t)mb * KCH * 4096 + lane * 8;
    // B frag halves offset: nb*KCH*4096 + k0*4096 + (wave_n*4+tn)*512 + lane*8
    const short* Bbase = Whi + (size_t)nb * KCH * 4096
                             + ((size_t)(wave_n * 4) * 64 + lane) * 8;

#define STAGEA(k0_, buf_)                                                     \
    {                                                                         \
        _Pragma("unroll")                                                     \
        for (int j = 0; j < 2; ++j) {                                         \
            int c = wave * 2 + j;                                             \
            g2l16(Ablk + (size_t)((k0_) * 8 + c) * 512, &As[buf_][c][lane][0]);\
        }                                                                     \
    }

    half8 b[2][4];
    STAGEA(0, 0);
#pragma unroll
    for (int tn = 0; tn < 4; ++tn)
        b[0][tn] = *(const half8*)(Bbase + tn * 512);

#pragma unroll 2
    for (int k0 = 0; k0 < KCH; ++k0) {
        const int buf = k0 & 1;
        __syncthreads();                 // A(k0) resident (vmcnt drain here)
        if (k0 + 1 < KCH) {
            STAGEA(k0 + 1, buf ^ 1);     // hidden behind this k0's MFMAs
#pragma unroll
            for (int tn = 0; tn < 4; ++tn)
                b[buf ^ 1][tn] = *(const half8*)(Bbase + (size_t)(k0 + 1) * 4096
                                                 + tn * 512);
        }
        half8 a[4];
#pragma unroll
        for (int tm = 0; tm < 4; ++tm)
            a[tm] = *(const half8*)&As[buf][wave_m * 4 + tm][lane][0];
#pragma unroll
        for (int tm = 0; tm < 4; ++tm)
#pragma unroll
            for (int tn = 0; tn < 4; ++tn)
                acc[tm][tn] = __builtin_amdgcn_mfma_f32_16x16x32_f16(
                                  a[tm], b[buf][tn], acc[tm][tn], 0, 0, 0);
    }
#undef STAGEA

    // --- epilogue: exp2 (logits pre-scaled by log2e), per-row reduce ---
    __syncthreads();
    const int colBase = nb * 128 + wave_n * 64;
    const int quad = lane >> 4;
    const int cidx = lane & 15;
#pragma unroll
    for (int tm = 0; tm < 4; ++tm) {
#pragma unroll
        for (int r = 0; r < 4; ++r) {
            float s = 0.0f;
#pragma unroll
            for (int tn = 0; tn < 4; ++tn) {
                int col = colBase + tn * 16 + cidx;
                if (col < VDIM) s += __builtin_amdgcn_exp2f(acc[tm][tn][r]);
            }
            s += __shfl_xor(s, 1);
            s += __shfl_xor(s, 2);
            s += __shfl_xor(s, 4);
            s += __shfl_xor(s, 8);
            if (cidx == 0) {
                int row = wave_m * 64 + tm * 16 + quad * 4 + r;
                atomicAdd(&rowsum[row], s);
            }
        }
    }
    __syncthreads();
    if (tid < 128) {
        atomicAdd(&g_sumexp[(size_t)mb * 128 + tid], (double)rowsum[tid]);
    }
}

// ---------------------------------------------------------------------------
// Fallback fp32 GEMM (round-2 kernel) if workspace is too small.
// ---------------------------------------------------------------------------
#define BM 128
#define BN 128
#define BK 16
#define LDPAD 4
__global__ __launch_bounds__(256)
void logits_expsum_kernel(const float* __restrict__ p2,
                          const float* __restrict__ p3,
                          const float* __restrict__ W,
                          double* __restrict__ g_sumexp)
{
    __shared__ float As[BK][BM + LDPAD];
    __shared__ float Bsh[BK][BN + LDPAD];
    __shared__ float rowsum[BM];

    const int tid     = threadIdx.x;
    const int rowBase = blockIdx.y * BM;
    const int colBase = blockIdx.x * BN;

    if (tid < BM) rowsum[tid] = 0.0f;

    float acc[8][8];
#pragma unroll
    for (int i = 0; i < 8; ++i)
#pragma unroll
        for (int j = 0; j < 8; ++j) acc[i][j] = 0.0f;

    const int ty = tid >> 4;
    const int tx = tid & 15;
    const int r0 = ty * 8;
    const int c0 = tx * 4;

    for (int k0 = 0; k0 < KDIM; k0 += BK) {
        __syncthreads();
#pragma unroll
        for (int l = 0; l < 2; ++l) {
            int id  = tid + l * 256;
            int row = id >> 2;
            int kq  = id & 3;
            int m   = rowBase + row;
            const float* src = (m < BT) ? (p2 + (size_t)m * KDIM)
                                        : (p3 + (size_t)(m - BT) * KDIM);
            float4 v = *(const float4*)(src + k0 + kq * 4);
            As[kq * 4 + 0][row] = v.x;
            As[kq * 4 + 1][row] = v.y;
            As[kq * 4 + 2][row] = v.z;
            As[kq * 4 + 3][row] = v.w;
        }
#pragma unroll
        for (int l = 0; l < 2; ++l) {
            int id  = tid + l * 256;
            int row = id >> 2;
            int kq  = id & 3;
            int c   = colBase + row;
            int cs  = (c < VDIM) ? c : (VDIM - 1);
            float4 v = *(const float4*)(W + (size_t)cs * KDIM + k0 + kq * 4);
            Bsh[kq * 4 + 0][row] = v.x;
            Bsh[kq * 4 + 1][row] = v.y;
            Bsh[kq * 4 + 2][row] = v.z;
            Bsh[kq * 4 + 3][row] = v.w;
        }
        __syncthreads();
#pragma unroll
        for (int kk = 0; kk < BK; ++kk) {
            float a[8], bb[8];
            *(float4*)&a[0]  = *(const float4*)&As[kk][r0];
            *(float4*)&a[4]  = *(const float4*)&As[kk][r0 + 4];
            *(float4*)&bb[0] = *(const float4*)&Bsh[kk][c0];
            *(float4*)&bb[4] = *(const float4*)&Bsh[kk][64 + c0];
#pragma unroll
            for (int i = 0; i < 8; ++i)
#pragma unroll
                for (int j = 0; j < 8; ++j)
                    acc[i][j] = fmaf(a[i], bb[j], acc[i][j]);
        }
    }

    __syncthreads();
#pragma unroll
    for (int i = 0; i < 8; ++i) {
        float s = 0.0f;
#pragma unroll
        for (int j = 0; j < 8; ++j) {
            int c = colBase + ((j < 4) ? (c0 + j) : (64 + c0 + (j - 4)));
            if (c < VDIM) s += expf(acc[i][j]);
        }
        atomicAdd(&rowsum[r0 + i], s);
    }
    __syncthreads();
    if (tid < BM) {
        atomicAdd(&g_sumexp[rowBase + tid], (double)rowsum[tid]);
    }
}

// ---------------------------------------------------------------------------
// Kernel 2: per token — exact fp32 target logits + cosine.  NO atomics:
// writes per-token values; reduced by final_scalar_kernel (round-5 version
// did 4x4096 same-address f64 atomics -> serialized RMW tail).
// tokvals[t] = {nll2, nll3, cos, valid}
// ---------------------------------------------------------------------------
__global__ __launch_bounds__(256)
void finalize_tokens_kernel(const float* __restrict__ p2,
                            const float* __restrict__ p3,
                            const float* __restrict__ W,
                            const int*   __restrict__ targets,
                            const double* __restrict__ g_sumexp,
                            double* __restrict__ tokvals)
{
    const int t   = blockIdx.x;
    const int tid = threadIdx.x;
    const int tg  = targets[t];
    const bool valid = (tg >= 0);
    const float* w = W + (size_t)(valid ? tg : 0) * KDIM;
    const float* a = p2 + (size_t)t * KDIM;
    const float* b = p3 + (size_t)t * KDIM;

    float s22 = 0.f, s33 = 0.f, s23 = 0.f, s2w = 0.f, s3w = 0.f;
    for (int i = tid; i < KDIM; i += 256) {
        float x = a[i], y = b[i], ww = w[i];
        s22 = fmaf(x, x, s22);
        s33 = fmaf(y, y, s33);
        s23 = fmaf(x, y, s23);
        s2w = fmaf(x, ww, s2w);
        s3w = fmaf(y, ww, s3w);
    }
#pragma unroll
    for (int off = 32; off > 0; off >>= 1) {
        s22 += __shfl_down(s22, off);
        s33 += __shfl_down(s33, off);
        s23 += __shfl_down(s23, off);
        s2w += __shfl_down(s2w, off);
        s3w += __shfl_down(s3w, off);
    }
    __shared__ float sm[5][4];
    const int wv = tid >> 6, lane = tid & 63;
    if (lane == 0) {
        sm[0][wv] = s22; sm[1][wv] = s33; sm[2][wv] = s23;
        sm[3][wv] = s2w; sm[4][wv] = s3w;
    }
    __syncthreads();
    if (tid == 0) {
        float S22 = sm[0][0] + sm[0][1] + sm[0][2] + sm[0][3];
        float S33 = sm[1][0] + sm[1][1] + sm[1][2] + sm[1][3];
        float S23 = sm[2][0] + sm[2][1] + sm[2][2] + sm[2][3];
        float S2w = sm[3][0] + sm[3][1] + sm[3][2] + sm[3][3];
        float S3w = sm[4][0] + sm[4][1] + sm[4][2] + sm[4][3];

        float n2 = fmaxf(sqrtf(S22), EPS_COS);
        float n3 = fmaxf(sqrtf(S33), EPS_COS);

        double4 out;
        out.x = valid ? (log(g_sumexp[t])      - (double)S2w) : 0.0;
        out.y = valid ? (log(g_sumexp[BT + t]) - (double)S3w) : 0.0;
        out.z = (double)(S23 / (n2 * n3));
        out.w = valid ? 1.0 : 0.0;
        *(double4*)(tokvals + 4 * (size_t)t) = out;
    }
}

// ---------------------------------------------------------------------------
// Kernel 3: reduce tokvals -> output scalar (one 1024-thread block).
// ---------------------------------------------------------------------------
__global__ __launch_bounds__(1024)
void final_scalar_kernel(const double* __restrict__ tokvals,
                         float* __restrict__ out)
{
    const int tid = threadIdx.x;
    double s0 = 0.0, s1 = 0.0, s2 = 0.0, s3 = 0.0;
    for (int t = tid; t < BT; t += 1024) {
        double4 v = *(const double4*)(tokvals + 4 * (size_t)t);
        s0 += v.x; s1 += v.y; s2 += v.z; s3 += v.w;
    }
#pragma unroll
    for (int off = 32; off > 0; off >>= 1) {
        s0 += __shfl_down(s0, off);
        s1 += __shfl_down(s1, off);
        s2 += __shfl_down(s2, off);
        s3 += __shfl_down(s3, off);
    }
    __shared__ double sm[4][16];
    const int wv = tid >> 6, lane = tid & 63;
    if (lane == 0) { sm[0][wv] = s0; sm[1][wv] = s1; sm[2][wv] = s2; sm[3][wv] = s3; }
    __syncthreads();
    if (tid == 0) {
        double S0 = 0, S1 = 0, S2 = 0, S3 = 0;
#pragma unroll
        for (int i = 0; i < 16; ++i) { S0 += sm[0][i]; S1 += sm[1][i]; S2 += sm[2][i]; S3 += sm[3][i]; }
        double cnt = (S3 > 0.0) ? S3 : 1.0;
        double loss_p2 = S0 / cnt;
        double loss_p3 = S1 / cnt;
        double reward_loss = -REWARD_SCALE * (loss_p2 - loss_p3);
        double divergence  =  DIV_WEIGHT * (S2 / (double)BT);
        out[0] = (float)(reward_loss + divergence);
    }
}

// ---------------------------------------------------------------------------
extern "C" void kernel_launch(void* const* d_in, const int* in_sizes, int n_in,
                              void* d_out, int out_size, void* d_ws, size_t ws_size,
                              hipStream_t stream)
{
    const float* p2  = (const float*)d_in[0];   // [2,2048,768] fp32
    const float* p3  = (const float*)d_in[1];   // [2,2048,768] fp32
    const float* W   = (const float*)d_in[2];   // [50257,768] fp32
    const int*   tgt = (const int*)d_in[3];     // [2,2048]

    double* g_sumexp = (double*)d_ws;                    // 8192 doubles (64 KB)
    double* tokvals  = g_sumexp + M_TOT;                 // 16384 doubles (128 KB)
    char*   fragbase = (char*)d_ws + 196608;

    hipMemsetAsync(d_ws, 0, 65536, stream);   // g_sumexp only

    const size_t need = 196608 + (size_t)A_FRAGS * 16 + (size_t)W_FRAGS * 16;
    if (ws_size >= need) {
        short* Ahi = (short*)fragbase;
        short* Whi = Ahi + (size_t)A_FRAGS * 8;

        convert_A_kernel<<<dim3(64, KCH), dim3(256), 0, stream>>>(p2, p3, Ahi);
        convert_W_kernel<<<dim3(NBLK, KCH), dim3(256), 0, stream>>>(W, Whi);
        // grid.x = mb fast: co-resident blocks share mb (A L1/L2-hot) and
        // spread nb within an XCD (B slices L2-resident).
        gemm_f16_kernel<<<dim3(64, NBLK), dim3(256), 0, stream>>>(Ahi, Whi, g_sumexp);
    } else {
        logits_expsum_kernel<<<dim3(NBLK, 64), dim3(256), 0, stream>>>(p2, p3, W, g_sumexp);
    }

    finalize_tokens_kernel<<<dim3(BT), dim3(256), 0, stream>>>(
        p2, p3, W, tgt, g_sumexp, tokvals);

    final_scalar_kernel<<<dim3(1), dim3(1024), 0, stream>>>(tokvals, (float*)d_out);
}